// Round 7
// baseline (633.449 us; speedup 1.0000x reference)
//
#include <hip/hip_runtime.h>
#include <hip/hip_bf16.h>

#define B_ 4
#define N_ 256
#define D_ 256
#define KG_ 128
#define EPS_ 1e-5f

typedef __bf16 bf16x8 __attribute__((ext_vector_type(8)));
typedef __bf16 bf16x4 __attribute__((ext_vector_type(4)));
typedef float  f32x4v __attribute__((ext_vector_type(4)));

// ---------------------------------------------------------------------------
// S1: W_kcT[d][g] = sum_k W_kg[g][k] * Wc[k][d]   (bf16, transposed)
//     bias_tot[d] = sum_k b_kg[k] * Wc[k][d] + b1l[d]
// ---------------------------------------------------------------------------
__global__ __launch_bounds__(256) void s1_kernel(
    const float* __restrict__ Wkg, const float* __restrict__ W1l,
    const float* __restrict__ bkg, const float* __restrict__ b1l,
    __bf16* __restrict__ WkcT, float* __restrict__ biastot)
{
    const int d = threadIdx.x;
    if (blockIdx.x == KG_) {
        float acc = 0.f;
        for (int k = 0; k < D_; ++k)
            acc += bkg[k] * W1l[(2 * D_ + k) * D_ + d];
        biastot[d] = acc + b1l[d];
        return;
    }
    const int g = blockIdx.x;
    float acc = 0.f;
    for (int k = 0; k < D_; ++k)
        acc += Wkg[g * D_ + k] * W1l[(2 * D_ + k) * D_ + d];
    WkcT[d * KG_ + g] = (__bf16)acc;
}

// ---------------------------------------------------------------------------
// S2: a_pb[row][d] = (h @ Wa)[row][d] + bias_tot[d]   (fp32)
//     bb  [row][d] = (h @ Wb)[row][d]                  (bf16)
// ---------------------------------------------------------------------------
__global__ __launch_bounds__(256) void s2_kernel(
    const float* __restrict__ hin, const float* __restrict__ W1l,
    const float* __restrict__ biastot,
    float* __restrict__ apb, __bf16* __restrict__ bbout)
{
    __shared__ float hT[D_][4];
    const int tid = threadIdx.x;
    const int R = blockIdx.x * 4;
    {
        const int r = tid & 3, c4 = (tid >> 2) << 2;
        const float4 v = *(const float4*)(hin + (R + r) * D_ + c4);
        hT[c4 + 0][r] = v.x; hT[c4 + 1][r] = v.y;
        hT[c4 + 2][r] = v.z; hT[c4 + 3][r] = v.w;
    }
    __syncthreads();
    float aa[4] = {0.f, 0.f, 0.f, 0.f};
    float ab[4] = {0.f, 0.f, 0.f, 0.f};
#pragma unroll 4
    for (int e = 0; e < D_; ++e) {
        const float wa = W1l[e * D_ + tid];
        const float wb = W1l[(D_ + e) * D_ + tid];
        const float4 hv = *(const float4*)&hT[e][0];
        aa[0] += hv.x * wa; aa[1] += hv.y * wa; aa[2] += hv.z * wa; aa[3] += hv.w * wa;
        ab[0] += hv.x * wb; ab[1] += hv.y * wb; ab[2] += hv.z * wb; ab[3] += hv.w * wb;
    }
    const float bt = biastot[tid];
#pragma unroll
    for (int r = 0; r < 4; ++r) {
        apb[(R + r) * D_ + tid]    = aa[r] + bt;
        bbout[(R + r) * D_ + tid]  = (__bf16)ab[r];
    }
}

__device__ __forceinline__ bf16x8 cvt8(const f32x4v a, const f32x4v b) {
    bf16x8 v;
    v[0] = (__bf16)a[0]; v[1] = (__bf16)a[1]; v[2] = (__bf16)a[2]; v[3] = (__bf16)a[3];
    v[4] = (__bf16)b[0]; v[5] = (__bf16)b[1]; v[6] = (__bf16)b[2]; v[7] = (__bf16)b[3];
    return v;
}

// E prefetch into 8 NAMED scalars (no arrays, no pointers -> no scratch)
#define ELOAD(p, jj) do {                                   \
    const float* s_ = esrc + (jj) * 16 * KG_;               \
    p##0 = *(const f32x4v*)(s_);                            \
    p##1 = *(const f32x4v*)(s_ + 4);                        \
    p##2 = *(const f32x4v*)(s_ + 32);                       \
    p##3 = *(const f32x4v*)(s_ + 36);                       \
    p##4 = *(const f32x4v*)(s_ + 64);                       \
    p##5 = *(const f32x4v*)(s_ + 68);                       \
    p##6 = *(const f32x4v*)(s_ + 96);                       \
    p##7 = *(const f32x4v*)(s_ + 100);                      \
} while (0)

#define DCOMP(p, jj) do {                                                     \
    const bf16x8 af0_ = cvt8(p##0, p##1);                                     \
    const bf16x8 af1_ = cvt8(p##2, p##3);                                     \
    const bf16x8 af2_ = cvt8(p##4, p##5);                                     \
    const bf16x8 af3_ = cvt8(p##6, p##7);                                     \
    f32x4v a0_ = {0.f,0.f,0.f,0.f}, a1_ = a0_, a2_ = a0_, a3_ = a0_;          \
    a0_ = __builtin_amdgcn_mfma_f32_16x16x32_bf16(wf[0][0], af0_, a0_, 0,0,0);\
    a1_ = __builtin_amdgcn_mfma_f32_16x16x32_bf16(wf[1][0], af0_, a1_, 0,0,0);\
    a2_ = __builtin_amdgcn_mfma_f32_16x16x32_bf16(wf[2][0], af0_, a2_, 0,0,0);\
    a3_ = __builtin_amdgcn_mfma_f32_16x16x32_bf16(wf[3][0], af0_, a3_, 0,0,0);\
    a0_ = __builtin_amdgcn_mfma_f32_16x16x32_bf16(wf[0][1], af1_, a0_, 0,0,0);\
    a1_ = __builtin_amdgcn_mfma_f32_16x16x32_bf16(wf[1][1], af1_, a1_, 0,0,0);\
    a2_ = __builtin_amdgcn_mfma_f32_16x16x32_bf16(wf[2][1], af1_, a2_, 0,0,0);\
    a3_ = __builtin_amdgcn_mfma_f32_16x16x32_bf16(wf[3][1], af1_, a3_, 0,0,0);\
    a0_ = __builtin_amdgcn_mfma_f32_16x16x32_bf16(wf[0][2], af2_, a0_, 0,0,0);\
    a1_ = __builtin_amdgcn_mfma_f32_16x16x32_bf16(wf[1][2], af2_, a1_, 0,0,0);\
    a2_ = __builtin_amdgcn_mfma_f32_16x16x32_bf16(wf[2][2], af2_, a2_, 0,0,0);\
    a3_ = __builtin_amdgcn_mfma_f32_16x16x32_bf16(wf[3][2], af2_, a3_, 0,0,0);\
    a0_ = __builtin_amdgcn_mfma_f32_16x16x32_bf16(wf[0][3], af3_, a0_, 0,0,0);\
    a1_ = __builtin_amdgcn_mfma_f32_16x16x32_bf16(wf[1][3], af3_, a1_, 0,0,0);\
    a2_ = __builtin_amdgcn_mfma_f32_16x16x32_bf16(wf[2][3], af3_, a2_, 0,0,0);\
    a3_ = __builtin_amdgcn_mfma_f32_16x16x32_bf16(wf[3][3], af3_, a3_, 0,0,0);\
    const int row_ = (jj) * 16 + l15;                                         \
    const float adjj_ = adjL[row_];                                           \
    const __bf16* brow_ = bbBase + row_ * D_ + dw + lg * 4;                   \
    const bf16x4 bv0_ = *(const bf16x4*)(brow_);                              \
    const bf16x4 bv1_ = *(const bf16x4*)(brow_ + 16);                         \
    const bf16x4 bv2_ = *(const bf16x4*)(brow_ + 32);                         \
    const bf16x4 bv3_ = *(const bf16x4*)(brow_ + 48);                         \
    for (int q = 0; q < 4; ++q) {                                             \
        racc[0][q] += fmaxf(a0_[q] + apbv[0][q] + (float)bv0_[q], 0.f) * adjj_;\
        racc[1][q] += fmaxf(a1_[q] + apbv[1][q] + (float)bv1_[q], 0.f) * adjj_;\
        racc[2][q] += fmaxf(a2_[q] + apbv[2][q] + (float)bv2_[q], 0.f) * adjj_;\
        racc[3][q] += fmaxf(a3_[q] + apbv[3][q] + (float)bv3_[q], 0.f) * adjj_;\
    }                                                                          \
} while (0)

// ---------------------------------------------------------------------------
// BIG: one block per (b,i). NO LDS / NO barriers in the main loop.
// Per jj-subtile (16 j): E read DIRECT from global (coalesced: wave covers
// 16 x 128-B row segments per kk), cvt->bf16, 16 MFMA, epilogue reads bb
// direct from L2. Depth-1 ping-pong prefetch in NAMED registers.
// MFMA operand-swapped: D[d][j]; lane (l15=j, lg,q = d-quad).
// ---------------------------------------------------------------------------
__global__ __launch_bounds__(256, 2) void big_kernel(
    const float* __restrict__ rel, const int* __restrict__ adj,
    const __bf16* __restrict__ WkcT, const float* __restrict__ apb,
    const __bf16* __restrict__ bb, const float* __restrict__ W2l,
    const float* __restrict__ b2l, const float* __restrict__ hin,
    const float* __restrict__ gmm, const float* __restrict__ bta,
    float* __restrict__ hout)
{
    __shared__ float adjL[N_];
    __shared__ float rL[D_];
    __shared__ float red[8];
    __shared__ float sdeg;

    const int tid = threadIdx.x;
    const int lane = tid & 63;
    const int w = tid >> 6;
    const int l15 = lane & 15;
    const int lg = lane >> 4;     // 0..3
    const int bi = blockIdx.x;    // b*256 + i
    const int dw = w * 64;

    const float*  Ebase  = rel + (size_t)bi * N_ * KG_;
    const __bf16* bbBase = bb + (size_t)(bi >> 8) * N_ * D_;

    // persistent Wkc fragments (A-operand): row(d)=l15, k=kk*32+lg*8
    bf16x8 wf[4][4];
#pragma unroll
    for (int nb = 0; nb < 4; ++nb)
#pragma unroll
        for (int kk = 0; kk < 4; ++kk)
            wf[nb][kk] = *(const bf16x8*)(WkcT + (dw + nb * 16 + l15) * KG_ + kk * 32 + lg * 8);

    f32x4v apbv[4];   // d = dw + nb*16 + lg*4 + q
#pragma unroll
    for (int nb = 0; nb < 4; ++nb)
        apbv[nb] = *(const f32x4v*)(apb + bi * D_ + dw + nb * 16 + lg * 4);

    adjL[tid] = (float)adj[bi * N_ + tid];
    __syncthreads();   // adjL ready (only barrier before the tail)

    float racc[4][4] = {};

    // lane's E row pointer: row = jj*16 + l15, k-base = lg*8
    const float* esrc = Ebase + l15 * KG_ + lg * 8;

    f32x4v pa0, pa1, pa2, pa3, pa4, pa5, pa6, pa7;
    f32x4v pb0, pb1, pb2, pb3, pb4, pb5, pb6, pb7;

    ELOAD(pa, 0);
#pragma unroll
    for (int jj = 0; jj < 16; jj += 2) {
        ELOAD(pb, jj + 1);
        DCOMP(pa, jj);
        if (jj + 2 < 16) ELOAD(pa, jj + 2);
        DCOMP(pb, jj + 1);
    }

    // ---- reduce racc over the 16 l15-lanes (j) -> rL[d] ----
#pragma unroll
    for (int nb = 0; nb < 4; ++nb) {
        float v0 = racc[nb][0], v1 = racc[nb][1], v2 = racc[nb][2], v3 = racc[nb][3];
#pragma unroll
        for (int off = 1; off <= 8; off <<= 1) {
            v0 += __shfl_xor(v0, off, 64);
            v1 += __shfl_xor(v1, off, 64);
            v2 += __shfl_xor(v2, off, 64);
            v3 += __shfl_xor(v3, off, 64);
        }
        if (l15 == 0) {
            float4 o; o.x = v0; o.y = v1; o.z = v2; o.w = v3;
            *(float4*)&rL[dw + nb * 16 + lg * 4] = o;
        }
    }
    if (w == 0) {
        float s = adjL[lane] + adjL[lane + 64] + adjL[lane + 128] + adjL[lane + 192];
#pragma unroll
        for (int off = 32; off >= 1; off >>= 1) s += __shfl_xor(s, off, 64);
        if (lane == 0) sdeg = s;
    }
    __syncthreads();

    // ---- msg = r @ W2 (fp32), residual, LayerNorm ----
    const int d = tid;
    float m0 = 0.f, m1 = 0.f, m2 = 0.f, m3 = 0.f;
    for (int e = 0; e < D_; e += 4) {
        const float4 rv = *(const float4*)&rL[e];
        m0 += rv.x * W2l[(e + 0) * D_ + d];
        m1 += rv.y * W2l[(e + 1) * D_ + d];
        m2 += rv.z * W2l[(e + 2) * D_ + d];
        m3 += rv.w * W2l[(e + 3) * D_ + d];
    }
    const float t = hin[bi * D_ + d] + (m0 + m1) + (m2 + m3) + sdeg * b2l[d];

    float s = t, sq = t * t;
#pragma unroll
    for (int off = 32; off >= 1; off >>= 1) {
        s  += __shfl_xor(s, off, 64);
        sq += __shfl_xor(sq, off, 64);
    }
    if (lane == 0) { red[w] = s; red[4 + w] = sq; }
    __syncthreads();
    const float S  = red[0] + red[1] + red[2] + red[3];
    const float SQ = red[4] + red[5] + red[6] + red[7];
    const float mu = S * (1.f / D_);
    const float var = SQ * (1.f / D_) - mu * mu;
    const float rstd = rsqrtf(var + EPS_);
    hout[bi * D_ + d] = (t - mu) * rstd * gmm[d] + bta[d];
}

// ---------------------------------------------------------------------------
extern "C" void kernel_launch(void* const* d_in, const int* in_sizes, int n_in,
                              void* d_out, int out_size, void* d_ws, size_t ws_size,
                              hipStream_t stream)
{
    const float* node  = (const float*)d_in[0];
    const float* rel   = (const float*)d_in[1];
    const int*   adj   = (const int*)d_in[2];
    const float* Wkg   = (const float*)d_in[3];
    const float* bkg   = (const float*)d_in[4];
    const float* W1    = (const float*)d_in[5];
    const float* b1    = (const float*)d_in[6];
    const float* W2    = (const float*)d_in[7];
    const float* b2    = (const float*)d_in[8];
    const float* gamma = (const float*)d_in[9];
    const float* beta  = (const float*)d_in[10];
    float* out = (float*)d_out;

    char* ws = (char*)d_ws;
    float*  h1    = (float*)(ws);                       // 1 MB
    float*  apb   = (float*)(ws + (1 << 20));           // 1 MB
    __bf16* bbuf  = (__bf16*)(ws + (2 << 20));          // 512 KB
    float*  bias  = (float*)(ws + (3 << 20));           // 1 KB
    __bf16* WkcT  = (__bf16*)(ws + (3 << 20) + 4096);   // 64 KB

    for (int l = 0; l < 2; ++l) {
        const float* W1l = W1 + (size_t)l * 3 * D_ * D_;
        const float* hin = (l == 0) ? node : h1;
        float* hout = (l == 1) ? out : h1;

        s1_kernel<<<KG_ + 1, 256, 0, stream>>>(Wkg, W1l, bkg, b1 + l * D_, WkcT, bias);
        s2_kernel<<<(B_ * N_) / 4, 256, 0, stream>>>(hin, W1l, bias, apb, bbuf);
        big_kernel<<<B_ * N_, 256, 0, stream>>>(rel, adj, WkcT, apb, bbuf,
                                                W2 + (size_t)l * D_ * D_, b2 + l * D_,
                                                hin, gamma, beta, hout);
    }
}

// Round 8
// 229.151 us; speedup vs baseline: 2.7643x; 2.7643x over previous
//
#include <hip/hip_runtime.h>
#include <hip/hip_bf16.h>

#define B_ 4
#define N_ 256
#define D_ 256
#define KG_ 128
#define EPS_ 1e-5f

typedef __bf16 bf16x8 __attribute__((ext_vector_type(8)));
typedef __bf16 bf16x4 __attribute__((ext_vector_type(4)));
typedef float  f32x4v __attribute__((ext_vector_type(4)));

__device__ __forceinline__ void gload16(const void* g, void* l) {
    __builtin_amdgcn_global_load_lds(
        (const __attribute__((address_space(1))) uint32_t*)g,
        (__attribute__((address_space(3))) uint32_t*)l, 16, 0, 0);
}

// ---------------------------------------------------------------------------
// S1: W_kcT[d][g] = sum_k W_kg[g][k] * Wc[k][d]   (bf16, transposed)
//     bias_tot[d] = sum_k b_kg[k] * Wc[k][d] + b1l[d]
// ---------------------------------------------------------------------------
__global__ __launch_bounds__(256) void s1_kernel(
    const float* __restrict__ Wkg, const float* __restrict__ W1l,
    const float* __restrict__ bkg, const float* __restrict__ b1l,
    __bf16* __restrict__ WkcT, float* __restrict__ biastot)
{
    const int d = threadIdx.x;
    if (blockIdx.x == KG_) {
        float acc = 0.f;
        for (int k = 0; k < D_; ++k)
            acc += bkg[k] * W1l[(2 * D_ + k) * D_ + d];
        biastot[d] = acc + b1l[d];
        return;
    }
    const int g = blockIdx.x;
    float acc = 0.f;
    for (int k = 0; k < D_; ++k)
        acc += Wkg[g * D_ + k] * W1l[(2 * D_ + k) * D_ + d];
    WkcT[d * KG_ + g] = (__bf16)acc;
}

// ---------------------------------------------------------------------------
// S2: a_pb[row][d] = (h @ Wa)[row][d] + bias_tot[d]   (fp32)
//     bb  [row][d] = (h @ Wb)[row][d]                  (bf16)
// ---------------------------------------------------------------------------
__global__ __launch_bounds__(256) void s2_kernel(
    const float* __restrict__ hin, const float* __restrict__ W1l,
    const float* __restrict__ biastot,
    float* __restrict__ apb, __bf16* __restrict__ bbout)
{
    __shared__ float hT[D_][4];
    const int tid = threadIdx.x;
    const int R = blockIdx.x * 4;
    {
        const int r = tid & 3, c4 = (tid >> 2) << 2;
        const float4 v = *(const float4*)(hin + (R + r) * D_ + c4);
        hT[c4 + 0][r] = v.x; hT[c4 + 1][r] = v.y;
        hT[c4 + 2][r] = v.z; hT[c4 + 3][r] = v.w;
    }
    __syncthreads();
    float aa[4] = {0.f, 0.f, 0.f, 0.f};
    float ab[4] = {0.f, 0.f, 0.f, 0.f};
#pragma unroll 4
    for (int e = 0; e < D_; ++e) {
        const float wa = W1l[e * D_ + tid];
        const float wb = W1l[(D_ + e) * D_ + tid];
        const float4 hv = *(const float4*)&hT[e][0];
        aa[0] += hv.x * wa; aa[1] += hv.y * wa; aa[2] += hv.z * wa; aa[3] += hv.w * wa;
        ab[0] += hv.x * wb; ab[1] += hv.y * wb; ab[2] += hv.z * wb; ab[3] += hv.w * wb;
    }
    const float bt = biastot[tid];
#pragma unroll
    for (int r = 0; r < 4; ++r) {
        apb[(R + r) * D_ + tid]    = aa[r] + bt;
        bbout[(R + r) * D_ + tid]  = (__bf16)ab[r];
    }
}

// ---------------------------------------------------------------------------
// BIG (templated for ablation).  MODE 0 = full (real output).
//   MODE 1 = staging+barriers only.   MODE 2 = compute+barriers only.
//   MODE 4 = reduce + W2 tail + LN only.
// Structure identical to R5: 4 bulk rounds (64 j each), single-buffered:
//   Et: 64j x 128k bf16 (16 KB), reg-staged f32->bf16, XOR-swizzled rows.
//   Bt: 64j x 256d bf16 (32 KB), gload_lds with XOR source-swizzle.
// ---------------------------------------------------------------------------
template<int MODE>
__global__ __launch_bounds__(256, 2) void big_kernel(
    const float* __restrict__ rel, const int* __restrict__ adj,
    const __bf16* __restrict__ WkcT, const float* __restrict__ apb,
    const __bf16* __restrict__ bb, const float* __restrict__ W2l,
    const float* __restrict__ b2l, const float* __restrict__ hin,
    const float* __restrict__ gmm, const float* __restrict__ bta,
    float* __restrict__ hout)
{
    constexpr bool DO_STAGE = (MODE == 0 || MODE == 1);
    constexpr bool DO_COMP  = (MODE == 0 || MODE == 2);
    constexpr bool DO_TAIL  = (MODE == 0 || MODE == 4);

    __shared__ __align__(16) __bf16 Et[64 * KG_];   // 16 KB
    __shared__ __align__(16) __bf16 Bt[64 * D_];    // 32 KB
    __shared__ float adjL[N_];
    __shared__ float rL[D_];
    __shared__ float red[8];
    __shared__ float sdeg;

    const int tid = threadIdx.x;
    const int lane = tid & 63;
    const int w = tid >> 6;
    const int l15 = lane & 15;
    const int lg = lane >> 4;     // 0..3
    const int bi = blockIdx.x;    // b*256 + i
    const int dw = w * 64;

    const float*  Ebase  = rel + (size_t)bi * N_ * KG_;
    const __bf16* bbBase = bb + (size_t)(bi >> 8) * N_ * D_;

    // persistent Wkc fragments (A-operand): row(d)=l15, k=kk*32+lg*8
    bf16x8 wf[4][4];
    if (DO_COMP) {
#pragma unroll
        for (int nb = 0; nb < 4; ++nb)
#pragma unroll
            for (int kk = 0; kk < 4; ++kk)
                wf[nb][kk] = *(const bf16x8*)(WkcT + (dw + nb * 16 + l15) * KG_ + kk * 32 + lg * 8);
    }

    f32x4v apbv[4];   // d = dw + nb*16 + lg*4 + q
    if (DO_COMP) {
#pragma unroll
        for (int nb = 0; nb < 4; ++nb)
            apbv[nb] = *(const f32x4v*)(apb + bi * D_ + dw + nb * 16 + lg * 4);
    }

    adjL[tid] = (float)adj[bi * N_ + tid];

    float racc[4][4] = {};

    for (int jq = 0; jq < 4; ++jq) {
        if (DO_STAGE) {
            // ---- stage Bt: 2048 16B-units, XOR source-swizzle ----
            const char* Gb = (const char*)(bbBase + jq * 64 * D_);
            char* ldsw = (char*)Bt + (tid & 192) * 16;
#pragma unroll
            for (int i = 0; i < 8; ++i) {
                const int u = tid + i * 256;
                const int gu = (u & ~31) | ((u & 31) ^ ((u >> 5) & 7));
                gload16(Gb + gu * 16, ldsw + i * 4096);
            }
            // ---- stage Et: 1024 bf16x8-units ----
#pragma unroll
            for (int rep = 0; rep < 4; ++rep) {
                const int v = tid + rep * 256;
                const int row = v >> 4;
                const int k0 = (v & 15) * 8;
                const float* s = Ebase + (jq * 64 + row) * KG_ + k0;
                const f32x4v fa = *(const f32x4v*)s;
                const f32x4v fb = *(const f32x4v*)(s + 4);
                bf16x8 v8;
                v8[0] = (__bf16)fa[0]; v8[1] = (__bf16)fa[1];
                v8[2] = (__bf16)fa[2]; v8[3] = (__bf16)fa[3];
                v8[4] = (__bf16)fb[0]; v8[5] = (__bf16)fb[1];
                v8[6] = (__bf16)fb[2]; v8[7] = (__bf16)fb[3];
                const int off = (row * 256 + k0 * 2) ^ ((row & 7) << 4);
                *(bf16x8*)((char*)Et + off) = v8;
            }
        }
        __syncthreads();

        if (DO_COMP) {
#pragma unroll
            for (int jj = 0; jj < 4; ++jj) {
                const int row = jj * 16 + l15;
                bf16x8 af[4];
#pragma unroll
                for (int kk = 0; kk < 4; ++kk) {
                    const int off = (row * 256 + kk * 64 + lg * 16) ^ ((row & 7) << 4);
                    af[kk] = *(const bf16x8*)((const char*)Et + off);
                }
                f32x4v acc[4];
#pragma unroll
                for (int nb = 0; nb < 4; ++nb) acc[nb] = (f32x4v){0.f, 0.f, 0.f, 0.f};
#pragma unroll
                for (int kk = 0; kk < 4; ++kk)
#pragma unroll
                    for (int nb = 0; nb < 4; ++nb)
                        acc[nb] = __builtin_amdgcn_mfma_f32_16x16x32_bf16(wf[nb][kk], af[kk], acc[nb], 0, 0, 0);

                const float adjj = adjL[jq * 64 + row];
#pragma unroll
                for (int nb = 0; nb < 4; ++nb) {
                    const int dbyte = w * 128 + nb * 32 + lg * 8;
                    const int su = (dbyte >> 4) ^ (row & 7);
                    const bf16x4 bv = *(const bf16x4*)((const char*)Bt + row * 512 + su * 16 + (dbyte & 15));
#pragma unroll
                    for (int q = 0; q < 4; ++q) {
                        float t = acc[nb][q] + apbv[nb][q] + (float)bv[q];
                        t = fmaxf(t, 0.f);
                        racc[nb][q] += t * adjj;
                    }
                }
            }
        }
        __syncthreads();
    }

    if (MODE == 1) {
        // keep the staged slabs observably live; measure staging structure only
        hout[bi * D_ + tid] = (float)Bt[tid] + (float)Et[tid];
        return;
    }
    if (MODE == 2) {
        float s = 0.f;
#pragma unroll
        for (int nb = 0; nb < 4; ++nb)
#pragma unroll
            for (int q = 0; q < 4; ++q) s += racc[nb][q];
        hout[bi * D_ + tid] = s;
        return;
    }

    // ---- reduce racc over the 16 l15-lanes (j) -> rL[d] ----
#pragma unroll
    for (int nb = 0; nb < 4; ++nb) {
        float v0 = racc[nb][0], v1 = racc[nb][1], v2 = racc[nb][2], v3 = racc[nb][3];
#pragma unroll
        for (int off = 1; off <= 8; off <<= 1) {
            v0 += __shfl_xor(v0, off, 64);
            v1 += __shfl_xor(v1, off, 64);
            v2 += __shfl_xor(v2, off, 64);
            v3 += __shfl_xor(v3, off, 64);
        }
        if (l15 == 0) {
            float4 o; o.x = v0; o.y = v1; o.z = v2; o.w = v3;
            *(float4*)&rL[dw + nb * 16 + lg * 4] = o;
        }
    }
    if (w == 0) {
        float s = adjL[lane] + adjL[lane + 64] + adjL[lane + 128] + adjL[lane + 192];
#pragma unroll
        for (int off = 32; off >= 1; off >>= 1) s += __shfl_xor(s, off, 64);
        if (lane == 0) sdeg = s;
    }
    __syncthreads();

    // ---- msg = r @ W2 (fp32), residual, LayerNorm ----
    const int d = tid;
    float m0 = 0.f, m1 = 0.f, m2 = 0.f, m3 = 0.f;
#pragma unroll 8
    for (int e = 0; e < D_; e += 4) {
        const float4 rv = *(const float4*)&rL[e];
        m0 += rv.x * W2l[(e + 0) * D_ + d];
        m1 += rv.y * W2l[(e + 1) * D_ + d];
        m2 += rv.z * W2l[(e + 2) * D_ + d];
        m3 += rv.w * W2l[(e + 3) * D_ + d];
    }
    const float t = hin[bi * D_ + d] + (m0 + m1) + (m2 + m3) + sdeg * b2l[d];

    float s = t, sq = t * t;
#pragma unroll
    for (int off = 32; off >= 1; off >>= 1) {
        s  += __shfl_xor(s, off, 64);
        sq += __shfl_xor(sq, off, 64);
    }
    if (lane == 0) { red[w] = s; red[4 + w] = sq; }
    __syncthreads();
    const float S  = red[0] + red[1] + red[2] + red[3];
    const float SQ = red[4] + red[5] + red[6] + red[7];
    const float mu = S * (1.f / D_);
    const float var = SQ * (1.f / D_) - mu * mu;
    const float rstd = rsqrtf(var + EPS_);
    hout[bi * D_ + d] = (t - mu) * rstd * gmm[d] + bta[d];
}

// ---------------------------------------------------------------------------
extern "C" void kernel_launch(void* const* d_in, const int* in_sizes, int n_in,
                              void* d_out, int out_size, void* d_ws, size_t ws_size,
                              hipStream_t stream)
{
    const float* node  = (const float*)d_in[0];
    const float* rel   = (const float*)d_in[1];
    const int*   adj   = (const int*)d_in[2];
    const float* Wkg   = (const float*)d_in[3];
    const float* bkg   = (const float*)d_in[4];
    const float* W1    = (const float*)d_in[5];
    const float* b1    = (const float*)d_in[6];
    const float* W2    = (const float*)d_in[7];
    const float* b2    = (const float*)d_in[8];
    const float* gamma = (const float*)d_in[9];
    const float* beta  = (const float*)d_in[10];
    float* out = (float*)d_out;

    char* ws = (char*)d_ws;
    float*  h1    = (float*)(ws);                       // 1 MB
    float*  apb   = (float*)(ws + (1 << 20));           // 1 MB
    __bf16* bbuf  = (__bf16*)(ws + (2 << 20));          // 512 KB
    float*  bias  = (float*)(ws + (3 << 20));           // 1 KB
    __bf16* WkcT  = (__bf16*)(ws + (3 << 20) + 4096);   // 64 KB

    for (int l = 0; l < 2; ++l) {
        const float* W1l = W1 + (size_t)l * 3 * D_ * D_;
        const float* hin = (l == 0) ? node : h1;
        float* hout = (l == 1) ? out : h1;

        s1_kernel<<<KG_ + 1, 256, 0, stream>>>(Wkg, W1l, bkg, b1 + l * D_, WkcT, bias);
        s2_kernel<<<(B_ * N_) / 4, 256, 0, stream>>>(hin, W1l, bias, apb, bbuf);
        big_kernel<0><<<B_ * N_, 256, 0, stream>>>(rel, adj, WkcT, apb, bbuf,
                                                   W2 + (size_t)l * D_ * D_, b2 + l * D_,
                                                   hin, gamma, beta, hout);
    }

    // ---- diagnostics (write to dead scratch h1; output already complete) ----
    big_kernel<1><<<B_ * N_, 256, 0, stream>>>(rel, adj, WkcT, apb, bbuf,
                                               W2 + (size_t)D_ * D_, b2 + D_,
                                               node, gamma, beta, h1);
    big_kernel<2><<<B_ * N_, 256, 0, stream>>>(rel, adj, WkcT, apb, bbuf,
                                               W2 + (size_t)D_ * D_, b2 + D_,
                                               node, gamma, beta, h1);
    big_kernel<4><<<B_ * N_, 256, 0, stream>>>(rel, adj, WkcT, apb, bbuf,
                                               W2 + (size_t)D_ * D_, b2 + D_,
                                               node, gamma, beta, h1);
}

// Round 9
// 186.920 us; speedup vs baseline: 3.3889x; 1.2259x over previous
//
#include <hip/hip_runtime.h>
#include <hip/hip_bf16.h>

#define B_ 4
#define N_ 256
#define D_ 256
#define KG_ 128
#define EPS_ 1e-5f

typedef __bf16 bf16x8 __attribute__((ext_vector_type(8)));
typedef __bf16 bf16x4 __attribute__((ext_vector_type(4)));
typedef float  f32x4v __attribute__((ext_vector_type(4)));

__device__ __forceinline__ void gload16(const void* g, void* l) {
    __builtin_amdgcn_global_load_lds(
        (const __attribute__((address_space(1))) uint32_t*)g,
        (__attribute__((address_space(3))) uint32_t*)l, 16, 0, 0);
}

// ---------------------------------------------------------------------------
// RELCVT: rel f32 (134 MB) -> bf16 (67 MB), one shot. Pure stream.
// ---------------------------------------------------------------------------
__global__ __launch_bounds__(256) void relcvt_kernel(
    const float* __restrict__ src, __bf16* __restrict__ dst)
{
    const size_t i = (size_t)blockIdx.x * 256 + threadIdx.x;  // 8-float unit
    const f32x4v a = *(const f32x4v*)(src + i * 8);
    const f32x4v b = *(const f32x4v*)(src + i * 8 + 4);
    bf16x8 v;
    v[0] = (__bf16)a[0]; v[1] = (__bf16)a[1]; v[2] = (__bf16)a[2]; v[3] = (__bf16)a[3];
    v[4] = (__bf16)b[0]; v[5] = (__bf16)b[1]; v[6] = (__bf16)b[2]; v[7] = (__bf16)b[3];
    *(bf16x8*)(dst + i * 8) = v;
}

// ---------------------------------------------------------------------------
// S1: W_kcT[d][g] = sum_k W_kg[g][k] * Wc[k][d]   (bf16, transposed)
//     bias_tot[d] = sum_k b_kg[k] * Wc[k][d] + b1l[d]
// ---------------------------------------------------------------------------
__global__ __launch_bounds__(256) void s1_kernel(
    const float* __restrict__ Wkg, const float* __restrict__ W1l,
    const float* __restrict__ bkg, const float* __restrict__ b1l,
    __bf16* __restrict__ WkcT, float* __restrict__ biastot)
{
    const int d = threadIdx.x;
    if (blockIdx.x == KG_) {
        float acc = 0.f;
        for (int k = 0; k < D_; ++k)
            acc += bkg[k] * W1l[(2 * D_ + k) * D_ + d];
        biastot[d] = acc + b1l[d];
        return;
    }
    const int g = blockIdx.x;
    float acc = 0.f;
    for (int k = 0; k < D_; ++k)
        acc += Wkg[g * D_ + k] * W1l[(2 * D_ + k) * D_ + d];
    WkcT[d * KG_ + g] = (__bf16)acc;
}

// ---------------------------------------------------------------------------
// S2: a_pb[row][d] = (h @ Wa)[row][d] + bias_tot[d]   (fp32)
//     bb  [row][d] = (h @ Wb)[row][d]                  (bf16)
// ---------------------------------------------------------------------------
__global__ __launch_bounds__(256) void s2_kernel(
    const float* __restrict__ hin, const float* __restrict__ W1l,
    const float* __restrict__ biastot,
    float* __restrict__ apb, __bf16* __restrict__ bbout)
{
    __shared__ float hT[D_][4];
    const int tid = threadIdx.x;
    const int R = blockIdx.x * 4;
    {
        const int r = tid & 3, c4 = (tid >> 2) << 2;
        const float4 v = *(const float4*)(hin + (R + r) * D_ + c4);
        hT[c4 + 0][r] = v.x; hT[c4 + 1][r] = v.y;
        hT[c4 + 2][r] = v.z; hT[c4 + 3][r] = v.w;
    }
    __syncthreads();
    float aa[4] = {0.f, 0.f, 0.f, 0.f};
    float ab[4] = {0.f, 0.f, 0.f, 0.f};
#pragma unroll 4
    for (int e = 0; e < D_; ++e) {
        const float wa = W1l[e * D_ + tid];
        const float wb = W1l[(D_ + e) * D_ + tid];
        const float4 hv = *(const float4*)&hT[e][0];
        aa[0] += hv.x * wa; aa[1] += hv.y * wa; aa[2] += hv.z * wa; aa[3] += hv.w * wa;
        ab[0] += hv.x * wb; ab[1] += hv.y * wb; ab[2] += hv.z * wb; ab[3] += hv.w * wb;
    }
    const float bt = biastot[tid];
#pragma unroll
    for (int r = 0; r < 4; ++r) {
        apb[(R + r) * D_ + tid]    = aa[r] + bt;
        bbout[(R + r) * D_ + tid]  = (__bf16)ab[r];
    }
}

// ---------------------------------------------------------------------------
// BIG: R5 structure (4 bulk rounds of 64 j, single-buffered slabs,
// 2-3 blocks/CU for inter-block stage/compute overlap).
//   BF16REL=1: Et staged via gload_lds direct from bf16 rel (zero VALU).
//   BF16REL=0: Et reg-staged f32->bf16 (fallback when ws too small).
//   Bt: 64j x 256d bf16 via gload_lds, XOR source-swizzle.
// MFMA operand-swapped: D[d][j]; lane (l15=j, lg,q = d-quad).
// ---------------------------------------------------------------------------
template<int BF16REL>
__global__ __launch_bounds__(256, 2) void big_kernel(
    const float* __restrict__ rel, const __bf16* __restrict__ relb,
    const int* __restrict__ adj,
    const __bf16* __restrict__ WkcT, const float* __restrict__ apb,
    const __bf16* __restrict__ bb, const float* __restrict__ W2l,
    const float* __restrict__ b2l, const float* __restrict__ hin,
    const float* __restrict__ gmm, const float* __restrict__ bta,
    float* __restrict__ hout)
{
    __shared__ __align__(16) __bf16 Et[64 * KG_];   // 16 KB
    __shared__ __align__(16) __bf16 Bt[64 * D_];    // 32 KB
    __shared__ float adjL[N_];
    __shared__ float rL[D_];
    __shared__ float red[8];
    __shared__ float sdeg;

    const int tid = threadIdx.x;
    const int lane = tid & 63;
    const int w = tid >> 6;
    const int l15 = lane & 15;
    const int lg = lane >> 4;     // 0..3
    const int bi = blockIdx.x;    // b*256 + i
    const int dw = w * 64;

    const float*  Ebase  = rel + (size_t)bi * N_ * KG_;
    const __bf16* EbaseB = relb + (size_t)bi * N_ * KG_;
    const __bf16* bbBase = bb + (size_t)(bi >> 8) * N_ * D_;

    // persistent Wkc fragments (A-operand): row(d)=l15, k=kk*32+lg*8
    bf16x8 wf[4][4];
#pragma unroll
    for (int nb = 0; nb < 4; ++nb)
#pragma unroll
        for (int kk = 0; kk < 4; ++kk)
            wf[nb][kk] = *(const bf16x8*)(WkcT + (dw + nb * 16 + l15) * KG_ + kk * 32 + lg * 8);

    f32x4v apbv[4];   // d = dw + nb*16 + lg*4 + q
#pragma unroll
    for (int nb = 0; nb < 4; ++nb)
        apbv[nb] = *(const f32x4v*)(apb + bi * D_ + dw + nb * 16 + lg * 4);

    adjL[tid] = (float)adj[bi * N_ + tid];

    float racc[4][4] = {};

    for (int jq = 0; jq < 4; ++jq) {
        // ---- stage Bt: 2048 16B-units; 32-unit rows, XOR key (u>>5)&7 ----
        {
            const char* Gb = (const char*)(bbBase + jq * 64 * D_);
            char* ldsw = (char*)Bt + (tid & 192) * 16;
#pragma unroll
            for (int i = 0; i < 8; ++i) {
                const int u = tid + i * 256;
                const int gu = (u & ~31) | ((u & 31) ^ ((u >> 5) & 7));
                gload16(Gb + gu * 16, ldsw + i * 4096);
            }
        }
        // ---- stage Et ----
        if (BF16REL) {
            // 1024 16B-units; 16-unit rows, XOR key (u>>4)&7; pure gload_lds
            const char* Gb = (const char*)(EbaseB + jq * 64 * KG_);
            char* ldsw = (char*)Et + (tid & 192) * 16;
#pragma unroll
            for (int i = 0; i < 4; ++i) {
                const int u = tid + i * 256;
                const int gu = (u & ~15) | ((u & 15) ^ ((u >> 4) & 7));
                gload16(Gb + gu * 16, ldsw + i * 4096);
            }
        } else {
            // reg-staged f32 -> bf16, XOR-swizzled rows (R5 path)
#pragma unroll
            for (int rep = 0; rep < 4; ++rep) {
                const int v = tid + rep * 256;
                const int row = v >> 4;
                const int k0 = (v & 15) * 8;
                const float* s = Ebase + (jq * 64 + row) * KG_ + k0;
                const f32x4v fa = *(const f32x4v*)s;
                const f32x4v fb = *(const f32x4v*)(s + 4);
                bf16x8 v8;
                v8[0] = (__bf16)fa[0]; v8[1] = (__bf16)fa[1];
                v8[2] = (__bf16)fa[2]; v8[3] = (__bf16)fa[3];
                v8[4] = (__bf16)fb[0]; v8[5] = (__bf16)fb[1];
                v8[6] = (__bf16)fb[2]; v8[7] = (__bf16)fb[3];
                const int off = (row * 256 + k0 * 2) ^ ((row & 7) << 4);
                *(bf16x8*)((char*)Et + off) = v8;
            }
        }
        __syncthreads();

        // ---- compute: 4 jj sub-tiles of 16 j ----
#pragma unroll
        for (int jj = 0; jj < 4; ++jj) {
            const int row = jj * 16 + l15;
            bf16x8 af[4];
#pragma unroll
            for (int kk = 0; kk < 4; ++kk) {
                const int off = (row * 256 + kk * 64 + lg * 16) ^ ((row & 7) << 4);
                af[kk] = *(const bf16x8*)((const char*)Et + off);
            }
            f32x4v acc[4];
#pragma unroll
            for (int nb = 0; nb < 4; ++nb) acc[nb] = (f32x4v){0.f, 0.f, 0.f, 0.f};
#pragma unroll
            for (int kk = 0; kk < 4; ++kk)
#pragma unroll
                for (int nb = 0; nb < 4; ++nb)
                    acc[nb] = __builtin_amdgcn_mfma_f32_16x16x32_bf16(wf[nb][kk], af[kk], acc[nb], 0, 0, 0);

            const float adjj = adjL[jq * 64 + row];
#pragma unroll
            for (int nb = 0; nb < 4; ++nb) {
                const int dbyte = w * 128 + nb * 32 + lg * 8;
                const int su = (dbyte >> 4) ^ (row & 7);
                const bf16x4 bv = *(const bf16x4*)((const char*)Bt + row * 512 + su * 16 + (dbyte & 15));
#pragma unroll
                for (int q = 0; q < 4; ++q) {
                    float t = acc[nb][q] + apbv[nb][q] + (float)bv[q];
                    t = fmaxf(t, 0.f);
                    racc[nb][q] += t * adjj;
                }
            }
        }
        __syncthreads();
    }

    // ---- reduce racc over the 16 l15-lanes (j) -> rL[d] ----
#pragma unroll
    for (int nb = 0; nb < 4; ++nb) {
        float v0 = racc[nb][0], v1 = racc[nb][1], v2 = racc[nb][2], v3 = racc[nb][3];
#pragma unroll
        for (int off = 1; off <= 8; off <<= 1) {
            v0 += __shfl_xor(v0, off, 64);
            v1 += __shfl_xor(v1, off, 64);
            v2 += __shfl_xor(v2, off, 64);
            v3 += __shfl_xor(v3, off, 64);
        }
        if (l15 == 0) {
            float4 o; o.x = v0; o.y = v1; o.z = v2; o.w = v3;
            *(float4*)&rL[dw + nb * 16 + lg * 4] = o;
        }
    }
    if (w == 0) {
        float s = adjL[lane] + adjL[lane + 64] + adjL[lane + 128] + adjL[lane + 192];
#pragma unroll
        for (int off = 32; off >= 1; off >>= 1) s += __shfl_xor(s, off, 64);
        if (lane == 0) sdeg = s;
    }
    __syncthreads();

    // ---- msg = r @ W2 (fp32), residual, LayerNorm ----
    const int d = tid;
    float m0 = 0.f, m1 = 0.f, m2 = 0.f, m3 = 0.f;
#pragma unroll 8
    for (int e = 0; e < D_; e += 4) {
        const float4 rv = *(const float4*)&rL[e];
        m0 += rv.x * W2l[(e + 0) * D_ + d];
        m1 += rv.y * W2l[(e + 1) * D_ + d];
        m2 += rv.z * W2l[(e + 2) * D_ + d];
        m3 += rv.w * W2l[(e + 3) * D_ + d];
    }
    const float t = hin[bi * D_ + d] + (m0 + m1) + (m2 + m3) + sdeg * b2l[d];

    float s = t, sq = t * t;
#pragma unroll
    for (int off = 32; off >= 1; off >>= 1) {
        s  += __shfl_xor(s, off, 64);
        sq += __shfl_xor(sq, off, 64);
    }
    if (lane == 0) { red[w] = s; red[4 + w] = sq; }
    __syncthreads();
    const float S  = red[0] + red[1] + red[2] + red[3];
    const float SQ = red[4] + red[5] + red[6] + red[7];
    const float mu = S * (1.f / D_);
    const float var = SQ * (1.f / D_) - mu * mu;
    const float rstd = rsqrtf(var + EPS_);
    hout[bi * D_ + d] = (t - mu) * rstd * gmm[d] + bta[d];
}

// ---------------------------------------------------------------------------
extern "C" void kernel_launch(void* const* d_in, const int* in_sizes, int n_in,
                              void* d_out, int out_size, void* d_ws, size_t ws_size,
                              hipStream_t stream)
{
    const float* node  = (const float*)d_in[0];
    const float* rel   = (const float*)d_in[1];
    const int*   adj   = (const int*)d_in[2];
    const float* Wkg   = (const float*)d_in[3];
    const float* bkg   = (const float*)d_in[4];
    const float* W1    = (const float*)d_in[5];
    const float* b1    = (const float*)d_in[6];
    const float* W2    = (const float*)d_in[7];
    const float* b2    = (const float*)d_in[8];
    const float* gamma = (const float*)d_in[9];
    const float* beta  = (const float*)d_in[10];
    float* out = (float*)d_out;

    char* ws = (char*)d_ws;
    float*  h1    = (float*)(ws);                       // 1 MB
    float*  apb   = (float*)(ws + (1 << 20));           // 1 MB
    __bf16* bbuf  = (__bf16*)(ws + (2 << 20));          // 512 KB
    float*  bias  = (float*)(ws + (3 << 20));           // 1 KB
    __bf16* WkcT  = (__bf16*)(ws + (3 << 20) + 4096);   // 64 KB
    __bf16* relb  = (__bf16*)(ws + (8 << 20));          // 64 MB (if it fits)

    const size_t relElems = (size_t)B_ * N_ * N_ * KG_;           // 33.5 M
    const bool useBF = ws_size >= ((size_t)(8 << 20) + relElems * 2);

    if (useBF)
        relcvt_kernel<<<(int)(relElems / 8 / 256), 256, 0, stream>>>(rel, relb);

    for (int l = 0; l < 2; ++l) {
        const float* W1l = W1 + (size_t)l * 3 * D_ * D_;
        const float* hin = (l == 0) ? node : h1;
        float* hout = (l == 1) ? out : h1;

        s1_kernel<<<KG_ + 1, 256, 0, stream>>>(Wkg, W1l, bkg, b1 + l * D_, WkcT, bias);
        s2_kernel<<<(B_ * N_) / 4, 256, 0, stream>>>(hin, W1l, bias, apb, bbuf);
        if (useBF)
            big_kernel<1><<<B_ * N_, 256, 0, stream>>>(rel, relb, adj, WkcT, apb, bbuf,
                                                       W2 + (size_t)l * D_ * D_, b2 + l * D_,
                                                       hin, gamma, beta, hout);
        else
            big_kernel<0><<<B_ * N_, 256, 0, stream>>>(rel, (const __bf16*)rel, adj, WkcT, apb, bbuf,
                                                       W2 + (size_t)l * D_ * D_, b2 + l * D_,
                                                       hin, gamma, beta, hout);
    }
}